// Round 5
// baseline (1188.209 us; speedup 1.0000x reference)
//
#include <hip/hip_runtime.h>

#define N_NODES 262144
#define BM 64
#define NTHREADS 512
#define NTILES 4096          // N_NODES / BM
#define NBLOCKS 512          // 2 per CU
#define TPB 8                // tiles per block

typedef short s16x8 __attribute__((ext_vector_type(8)));
typedef float f32x4 __attribute__((ext_vector_type(4)));

static __device__ __forceinline__ unsigned short f2bf(float f) {
  union { float f; unsigned u; } v; v.f = f;
  unsigned u = v.u;
  u += 0x7FFFu + ((u >> 16) & 1u);   // round-to-nearest-even
  return (unsigned short)(u >> 16);
}

static __device__ __forceinline__ unsigned long long pack4bf(f32x4 v) {
  unsigned u0 = (unsigned)f2bf(v.x) | ((unsigned)f2bf(v.y) << 16);
  unsigned u1 = (unsigned)f2bf(v.z) | ((unsigned)f2bf(v.w) << 16);
  return (unsigned long long)u0 | ((unsigned long long)u1 << 32);
}

static __device__ __forceinline__ float fsig(float x) {
  return __builtin_amdgcn_rcpf(1.0f + __expf(-x));
}
static __device__ __forceinline__ float ftanh(float x) {
  return 2.0f * __builtin_amdgcn_rcpf(1.0f + __expf(-2.0f * x)) - 1.0f;
}

// Weight prep:
//  Wh2[kb][n][ki] (16 x 64 x 32 bf16)  = W_hid[n][kb*32+ki]
//  W2 [kb][n][ki] ( 8 x 512 x 32 bf16) = k<128 ? W_ih[n][k] : W_hh[n][k-128]
//  biasg[512] = b_ih + b_hh
__global__ void prep_kernel(const float* __restrict__ Whid, const float* __restrict__ Wih,
                            const float* __restrict__ Whh, const float* __restrict__ bih,
                            const float* __restrict__ bhh,
                            unsigned short* __restrict__ oWh2, unsigned short* __restrict__ oW2,
                            float* __restrict__ oBias) {
  int t = blockIdx.x * 256 + threadIdx.x;
  if (t < 32768) {
    int kb = t >> 11, n = (t >> 5) & 63, ki = t & 31;
    oWh2[t] = f2bf(Whid[n * 512 + kb * 32 + ki]);
  }
  if (t < 131072) {
    int kb = t >> 14, n = (t >> 5) & 511, ki = t & 31;
    int k = kb * 32 + ki;
    float v = (k < 128) ? Wih[n * 128 + k] : Whh[n * 128 + (k - 128)];
    oW2[t] = f2bf(v);
  }
  if (t < 512) oBias[t] = bih[t] + bhh[t];
}

// LDS tiles: 64 rows x 256 bf16 (512B rows). XOR-swizzle spreads the
// 16-row-strided b128 column reads over 8 16B slots (G4).
#define SWZ(m, b) ((((m) * 512) + (b)) ^ (((m) & 7) << 4))

__global__ __launch_bounds__(NTHREADS, 4) void node_rnn_kernel(
    const float* __restrict__ Hv, const float* __restrict__ hvv,
    const float* __restrict__ xv, const float* __restrict__ hvp,
    const float* __restrict__ cvp, const int* __restrict__ tsm,
    const float* __restrict__ Wpos, const float* __restrict__ bpos,
    const float* __restrict__ bhid,
    const unsigned short* __restrict__ Wh2,
    const unsigned short* __restrict__ W2,
    const float* __restrict__ biasg,
    float* __restrict__ hvo, float* __restrict__ cvo)
{
  __shared__ __align__(16) char lds[65536];
  char* bufA = lds;            // h0 staging (K 0..255), later A2
  char* bufB = lds + 32768;    // h1 staging (K 256..511)

  const int tid = threadIdx.x;
  const int w   = tid >> 6;    // wave 0..7
  const int l   = tid & 63;
  const int l15 = l & 15;
  const int lk  = l >> 4;      // k-group 0..3
  const int wr  = w >> 2;      // phase-1 m-half
  const int wc  = w & 3;       // phase-1 n-slice
  const int blk = blockIdx.x;
  const int d   = 16 * w + l15;   // phase-2/3 gate-dim slice

  // ---- prologue: issue tile-0 h0 loads (hvv)
  f32x4 gcur[8];
  {
    int n0 = blk * BM;
#pragma unroll
    for (int it = 0; it < 8; ++it) {
      int p = tid + it * NTHREADS; int m = p >> 6, ch = p & 63;
      gcur[it] = *(const f32x4*)(hvv + (size_t)(n0 + m) * 256 + ch * 4);
    }
  }

#pragma unroll 1
  for (int t = 0; t < TPB; ++t) {
    const int tile  = blk + NBLOCKS * t;
    const int node0 = tile * BM;

    // ---- step 1: write h0 -> bufA (waits gcur vmcnt; hidden by prev phase 2)
#pragma unroll
    for (int it = 0; it < 8; ++it) {
      int p = tid + it * NTHREADS; int m = p >> 6, ch = p & 63;
      *(unsigned long long*)(bufA + SWZ(m, ch * 8)) = pack4bf(gcur[it]);
    }

    // ---- step 2: issue h1 loads (Hv) -> regs
    f32x4 gv[8];
#pragma unroll
    for (int it = 0; it < 8; ++it) {
      int p = tid + it * NTHREADS; int m = p >> 6, ch = p & 63;
      gv[it] = *(const f32x4*)(Hv + (size_t)(node0 + m) * 256 + ch * 4);
    }

    // ---- step 3: per-tile small loads (consumed much later; latency hidden)
    int myts = tsm[node0 + l];                           // coalesced, 1/lane
    unsigned long long actmask = __ballot(myts == 1);    // bit m = row m active
    float ex0[4], ex1[4];
#pragma unroll
    for (int it = 0; it < 4; ++it) {
      int p = tid + it * NTHREADS; int m = p >> 5;
      ex0[it] = xv[(size_t)(node0 + m) * 2 + 0];
      ex1[it] = xv[(size_t)(node0 + m) * 2 + 1];
    }
    f32x4 hvc[4];
#pragma unroll
    for (int it = 0; it < 4; ++it) {
      int p = tid + it * NTHREADS; int m = p >> 5, c4 = p & 31;
      hvc[it] = *(const f32x4*)(hvp + (size_t)(node0 + m) * 128 + c4 * 4);
    }
    float cvv[2][2][4];   // cold cvp: issue now, consume at tile end
#pragma unroll
    for (int H = 0; H < 2; ++H)
#pragma unroll
      for (int mi = 0; mi < 2; ++mi)
#pragma unroll
        for (int r = 0; r < 4; ++r) {
          int m = H * 32 + mi * 16 + lk * 4 + r;
          cvv[H][mi][r] = cvp[(size_t)(node0 + m) * 128 + d];
        }

    __syncthreads();   // B1: bufA (h0) staged

    // ---- phase 1a: acc += h0 @ Wh^T. Wave (wr,wc): rows wr*32+[0,32), cols wc*16+[0,16)
    f32x4 acc[2] = {f32x4{0.f,0.f,0.f,0.f}, f32x4{0.f,0.f,0.f,0.f}};
    const char* whb = (const char*)Wh2 + (16 * wc + l15) * 64 + lk * 16;
#pragma unroll
    for (int ks = 0; ks < 8; ++ks) {
      s16x8 bf = *(const s16x8*)(whb + ks * 4096);
#pragma unroll
      for (int mi = 0; mi < 2; ++mi) {
        s16x8 af = *(const s16x8*)(bufA + SWZ(wr * 32 + mi * 16 + l15, ks * 64 + lk * 16));
        acc[mi] = __builtin_amdgcn_mfma_f32_16x16x32_bf16(af, bf, acc[mi], 0, 0, 0);
      }
    }

    // ---- step 6: write h1 -> bufB (overlaps mfma-h0)
#pragma unroll
    for (int it = 0; it < 8; ++it) {
      int p = tid + it * NTHREADS; int m = p >> 6, ch = p & 63;
      *(unsigned long long*)(bufB + SWZ(m, ch * 8)) = pack4bf(gv[it]);
    }

    __syncthreads();   // B2: bufB staged AND all h0 reads done (bufA writable)

    // ---- phase 1b: acc += h1 @ Wh^T (reads bufB); A2 ev/hv writes overlap (bufA)
#pragma unroll
    for (int ks = 0; ks < 8; ++ks) {
      s16x8 bf = *(const s16x8*)(whb + (8 + ks) * 4096);
#pragma unroll
      for (int mi = 0; mi < 2; ++mi) {
        s16x8 af = *(const s16x8*)(bufB + SWZ(wr * 32 + mi * 16 + l15, ks * 64 + lk * 16));
        acc[mi] = __builtin_amdgcn_mfma_f32_16x16x32_bf16(af, bf, acc[mi], 0, 0, 0);
      }
    }
    // A2 = [e_v(cols 0..63) | a_v(64..127) | hv(128..255)] in bufA
#pragma unroll
    for (int it = 0; it < 4; ++it) {   // e_v, packed pairs
      int p = tid + it * NTHREADS; int m = p >> 5, jp = p & 31;
      float e0 = fmaxf(ex0[it] * Wpos[(2*jp  )*2] + ex1[it] * Wpos[(2*jp  )*2+1] + bpos[2*jp  ], 0.f);
      float e1 = fmaxf(ex0[it] * Wpos[(2*jp+1)*2] + ex1[it] * Wpos[(2*jp+1)*2+1] + bpos[2*jp+1], 0.f);
      unsigned u = (unsigned)f2bf(e0) | ((unsigned)f2bf(e1) << 16);
      *(unsigned*)(bufA + SWZ(m, jp * 4)) = u;
    }
#pragma unroll
    for (int it = 0; it < 4; ++it) {   // hv
      int p = tid + it * NTHREADS; int m = p >> 5, c4 = p & 31;
      *(unsigned long long*)(bufA + SWZ(m, 256 + c4 * 8)) = pack4bf(hvc[it]);
    }
    {                                   // a_v
      float bb = bhid[16 * wc + l15];
      int cb = (64 + 16 * wc + l15) * 2;
#pragma unroll
      for (int mi = 0; mi < 2; ++mi)
#pragma unroll
        for (int r = 0; r < 4; ++r) {
          int m = wr * 32 + mi * 16 + lk * 4 + r;
          *(unsigned short*)(bufA + SWZ(m, cb)) = f2bf(fmaxf(acc[mi][r] + bb, 0.f));
        }
    }

    __syncthreads();   // B3: A2 complete

    // ---- cross-tile prefetch: issue next tile's h0 loads NOW (covered by phase 2)
    {
      int tn = (t + 1 < TPB) ? (tile + NBLOCKS) : blk;   // clamp: last iter re-reads tile0 (unused)
      int n0n = tn * BM;
#pragma unroll
      for (int it = 0; it < 8; ++it) {
        int p = tid + it * NTHREADS; int m = p >> 6, ch = p & 63;
        gcur[it] = *(const f32x4*)(hvv + (size_t)(n0n + m) * 256 + ch * 4);
      }
    }

    float bs[4];
#pragma unroll
    for (int j = 0; j < 4; ++j) bs[j] = biasg[128 * j + d];

    // ---- phase 2 + pointwise, m-split halves (acc2 = 32 regs/half)
#pragma unroll
    for (int H = 0; H < 2; ++H) {
      float hov[2][4];   // hv passthrough values, L2-hot; cover with the mfma loop below
#pragma unroll
      for (int mi = 0; mi < 2; ++mi)
#pragma unroll
        for (int r = 0; r < 4; ++r)
          hov[mi][r] = hvp[(size_t)(node0 + H * 32 + mi * 16 + lk * 4 + r) * 128 + d];

      f32x4 acc2[2][4];
#pragma unroll
      for (int mi = 0; mi < 2; ++mi)
#pragma unroll
        for (int j = 0; j < 4; ++j) acc2[mi][j] = f32x4{0.f,0.f,0.f,0.f};

#pragma unroll
      for (int kk = 0; kk < 8; ++kk) {
        s16x8 a[2];
#pragma unroll
        for (int mi = 0; mi < 2; ++mi)
          a[mi] = *(const s16x8*)(bufA + SWZ(H * 32 + mi * 16 + l15, kk * 64 + lk * 16));
        const char* wb = (const char*)W2 + kk * 32768 + (size_t)(16 * w + l15) * 64 + lk * 16;
#pragma unroll
        for (int j = 0; j < 4; ++j) {
          s16x8 bf = *(const s16x8*)(wb + (size_t)(128 * j) * 64);
#pragma unroll
          for (int mi = 0; mi < 2; ++mi)
            acc2[mi][j] = __builtin_amdgcn_mfma_f32_16x16x32_bf16(a[mi], bf, acc2[mi][j], 0, 0, 0);
        }
      }
      if (H == 1) __syncthreads();   // B4: all bufA phase-2 reads done -> next tile may overwrite

      // pointwise rows H*32 .. H*32+31
#pragma unroll
      for (int mi = 0; mi < 2; ++mi) {
#pragma unroll
        for (int r = 0; r < 4; ++r) {
          int m = H * 32 + mi * 16 + lk * 4 + r;
          size_t node = (size_t)node0 + m;
          int act = (int)((actmask >> m) & 1ull);
          float gi = acc2[mi][0][r] + bs[0];
          float gf = acc2[mi][1][r] + bs[1];
          float gg = acc2[mi][2][r] + bs[2];
          float go = acc2[mi][3][r] + bs[3];
          float i_ = fsig(gi), f_ = fsig(gf), o_ = fsig(go);
          float g_ = ftanh(gg);
          float co = cvv[H][mi][r];
          float ho = hov[mi][r];
          float cn = f_ * co + i_ * g_;
          float hn = o_ * ftanh(cn);
          hvo[node * 128 + d] = act ? hn : ho;
          cvo[node * 128 + d] = act ? cn : co;
        }
      }
    }
  }
}

extern "C" void kernel_launch(void* const* d_in, const int* in_sizes, int n_in,
                              void* d_out, int out_size, void* d_ws, size_t ws_size,
                              hipStream_t stream) {
  const float* Hv   = (const float*)d_in[0];
  const float* hvv  = (const float*)d_in[1];
  const float* xv   = (const float*)d_in[2];
  const float* hvp  = (const float*)d_in[3];
  const float* cvp  = (const float*)d_in[4];
  const int*   tsm  = (const int*)d_in[5];
  const float* Wpos = (const float*)d_in[6];
  const float* bpos = (const float*)d_in[7];
  const float* Whid = (const float*)d_in[8];
  const float* bhid = (const float*)d_in[9];
  const float* Wih  = (const float*)d_in[10];
  const float* bih  = (const float*)d_in[11];
  const float* Whh  = (const float*)d_in[12];
  const float* bhh  = (const float*)d_in[13];

  unsigned short* wsWh2 = (unsigned short*)d_ws;   // 32768 bf16
  unsigned short* wsW2  = wsWh2 + 32768;           // 131072 bf16
  float* wsBias = (float*)(wsW2 + 131072);         // 512 f32

  prep_kernel<<<512, 256, 0, stream>>>(Whid, Wih, Whh, bih, bhh,
                                       wsWh2, wsW2, wsBias);

  float* hvo = (float*)d_out;
  float* cvo = hvo + (size_t)N_NODES * 128;
  node_rnn_kernel<<<NBLOCKS, NTHREADS, 0, stream>>>(
      Hv, hvv, xv, hvp, cvp, tsm, Wpos, bpos, bhid,
      wsWh2, wsW2, wsBias, hvo, cvo);
}

// Round 6
// 448.548 us; speedup vs baseline: 2.6490x; 2.6490x over previous
//
#include <hip/hip_runtime.h>

#define N_NODES 262144
#define BM 64
#define NTHREADS 512

typedef short s16x8 __attribute__((ext_vector_type(8)));
typedef float f32x4 __attribute__((ext_vector_type(4)));

// 2 f32 -> packed bf16x2 in one VOP3 (T12). lo16 = bf16(lo), hi16 = bf16(hi).
static __device__ __forceinline__ unsigned cvtpk(float lo, float hi) {
  unsigned r;
  asm("v_cvt_pk_bf16_f32 %0, %1, %2" : "=v"(r) : "v"(lo), "v"(hi));
  return r;
}

static __device__ __forceinline__ unsigned short f2bf(float f) {
  union { float f; unsigned u; } v; v.f = f;
  unsigned u = v.u;
  u += 0x7FFFu + ((u >> 16) & 1u);   // round-to-nearest-even
  return (unsigned short)(u >> 16);
}

static __device__ __forceinline__ unsigned long long pack4bf(f32x4 v) {
  unsigned u0 = cvtpk(v.x, v.y);
  unsigned u1 = cvtpk(v.z, v.w);
  return (unsigned long long)u0 | ((unsigned long long)u1 << 32);
}

static __device__ __forceinline__ float fsig(float x) {
  return __builtin_amdgcn_rcpf(1.0f + __expf(-x));
}
static __device__ __forceinline__ float ftanh(float x) {
  return 2.0f * __builtin_amdgcn_rcpf(1.0f + __expf(-2.0f * x)) - 1.0f;
}

// Weight prep:
//  Wh2[kb][n][ki] (16 x 64 x 32 bf16)  = W_hid[n][kb*32+ki]
//  W2 [kb][n][ki] ( 8 x 512 x 32 bf16) = k<128 ? W_ih[n][k] : W_hh[n][k-128]
//  biasg[512] = b_ih + b_hh
__global__ void prep_kernel(const float* __restrict__ Whid, const float* __restrict__ Wih,
                            const float* __restrict__ Whh, const float* __restrict__ bih,
                            const float* __restrict__ bhh,
                            unsigned short* __restrict__ oWh2, unsigned short* __restrict__ oW2,
                            float* __restrict__ oBias) {
  int t = blockIdx.x * 256 + threadIdx.x;
  if (t < 32768) {
    int kb = t >> 11, n = (t >> 5) & 63, ki = t & 31;
    oWh2[t] = f2bf(Whid[n * 512 + kb * 32 + ki]);
  }
  if (t < 131072) {
    int kb = t >> 14, n = (t >> 5) & 511, ki = t & 31;
    int k = kb * 32 + ki;
    float v = (k < 128) ? Wih[n * 128 + k] : Whh[n * 128 + (k - 128)];
    oW2[t] = f2bf(v);
  }
  if (t < 512) oBias[t] = bih[t] + bhh[t];
}

// Astage: 64 rows x 512 bf16 (1024B rows). XOR-swizzle spreads 16-row-strided
// b128 column reads over 8 16B slots (G4).
#define SWZA(m, b) ((((m) * 1024) + (b)) ^ (((m) & 7) << 4))
// A2: 64 rows x 256 bf16 (512B rows) = [e_v(64) | a_v(64) | hv(128)]. Aliases lds[0:32KB].
#define SWZ2(m, b) ((((m) * 512) + (b)) ^ (((m) & 7) << 4))

__global__ __launch_bounds__(NTHREADS, 4) void node_rnn_kernel(
    const float* __restrict__ Hv, const float* __restrict__ hvv,
    const float* __restrict__ xv, const float* __restrict__ hvp,
    const float* __restrict__ cvp, const int* __restrict__ tsm,
    const float* __restrict__ Wpos, const float* __restrict__ bpos,
    const float* __restrict__ bhid,
    const unsigned short* __restrict__ Wh2,
    const unsigned short* __restrict__ W2,
    const float* __restrict__ biasg,
    float* __restrict__ hvo, float* __restrict__ cvo)
{
  __shared__ __align__(16) char lds[65536];

  const int tid = threadIdx.x;
  const int w   = tid >> 6;      // wave 0..7
  const int l   = tid & 63;
  const int l15 = l & 15;
  const int lk  = l >> 4;        // k-group 0..3
  const int wr  = w >> 2;        // phase-1 m-half
  const int wc  = w & 3;         // phase-1 n-slice (16 cols)
  const int node0 = blockIdx.x * BM;
  const int d   = 16 * w + l15;  // phase-2/3 gate-dim slice

  // ---- Stage [hvv|Hv] (64 x 512 f32) -> bf16 Astage; coalesced f32x4, cvt_pk once
#pragma unroll
  for (int it = 0; it < 16; ++it) {
    int p = tid + it * NTHREADS;            // 64 rows x 128 f32x4-chunks
    int m = p >> 7, ch = p & 127;
    const float* src = (ch < 64) ? (hvv + (size_t)(node0 + m) * 256 + ch * 4)
                                 : (Hv  + (size_t)(node0 + m) * 256 + (ch - 64) * 4);
    f32x4 v = *(const f32x4*)src;
    *(unsigned long long*)(lds + SWZA(m, ch * 8)) = pack4bf(v);
  }

  // ---- small per-tile loads, issued behind the stage loads (covered by phase 1)
  unsigned long long actmask = __ballot(tsm[node0 + l] == 1);  // bit m = row m active

  unsigned evp[4];     // e_v as packed bf16 pairs
#pragma unroll
  for (int it = 0; it < 4; ++it) {
    int p = tid + it * NTHREADS;            // 64 rows x 32 pairs
    int m = p >> 5, jp = p & 31;
    float x0 = xv[(size_t)(node0 + m) * 2 + 0];
    float x1 = xv[(size_t)(node0 + m) * 2 + 1];
    float e0 = fmaxf(x0 * Wpos[(2*jp  )*2] + x1 * Wpos[(2*jp  )*2+1] + bpos[2*jp  ], 0.f);
    float e1 = fmaxf(x0 * Wpos[(2*jp+1)*2] + x1 * Wpos[(2*jp+1)*2+1] + bpos[2*jp+1], 0.f);
    evp[it] = cvtpk(e0, e1);
  }
  f32x4 hvc[4];        // hv_tm1 for the A2 tile
#pragma unroll
  for (int it = 0; it < 4; ++it) {
    int p = tid + it * NTHREADS;            // 64 rows x 32 f32x4-chunks
    int m = p >> 5, c4 = p & 31;
    hvc[it] = *(const f32x4*)(hvp + (size_t)(node0 + m) * 128 + c4 * 4);
  }

  __syncthreads();   // B1: Astage complete

  // ---- Phase 1: a_v = relu([hvv|Hv] @ Wh^T + bhid); wave (wr,wc): rows wr*32+[0,32), cols wc*16+[0,16)
  f32x4 acc[2] = {f32x4{0.f,0.f,0.f,0.f}, f32x4{0.f,0.f,0.f,0.f}};
  {
    const char* whb = (const char*)Wh2 + (wc * 16 + l15) * 64 + lk * 16;
#pragma unroll
    for (int ks = 0; ks < 16; ++ks) {
      s16x8 bf = *(const s16x8*)(whb + ks * 4096);
#pragma unroll
      for (int mi = 0; mi < 2; ++mi) {
        int m = wr * 32 + mi * 16 + l15;
        s16x8 af = *(const s16x8*)(lds + SWZA(m, ks * 64 + lk * 16));
        acc[mi] = __builtin_amdgcn_mfma_f32_16x16x32_bf16(af, bf, acc[mi], 0, 0, 0);
      }
    }
  }

  __syncthreads();   // B2: all Astage reads done; safe to overwrite with A2

  // ---- Build A2 = [e_v | a_v | hv] bf16
#pragma unroll
  for (int it = 0; it < 4; ++it) {
    int p = tid + it * NTHREADS;
    int m = p >> 5, jp = p & 31;
    *(unsigned*)(lds + SWZ2(m, jp * 4)) = evp[it];
  }
#pragma unroll
  for (int it = 0; it < 4; ++it) {
    int p = tid + it * NTHREADS;
    int m = p >> 5, c4 = p & 31;
    *(unsigned long long*)(lds + SWZ2(m, 256 + c4 * 8)) = pack4bf(hvc[it]);
  }
  {
    float bb = bhid[wc * 16 + l15];
    int cb = (64 + wc * 16 + l15) * 2;
#pragma unroll
    for (int mi = 0; mi < 2; ++mi) {
#pragma unroll
      for (int r = 0; r < 4; ++r) {
        int m = wr * 32 + mi * 16 + lk * 4 + r;
        float av = fmaxf(acc[mi][r] + bb, 0.0f);
        *(unsigned short*)(lds + SWZ2(m, cb)) = f2bf(av);
      }
    }
  }
  __syncthreads();   // B3: A2 complete

  // ---- prefetch pointwise operands NOW; the 64-MFMA phase-2 loop covers their latency
  float bs[4];
#pragma unroll
  for (int j = 0; j < 4; ++j) bs[j] = biasg[128 * j + d];
  float cvv[4][4], hov[4][4];
#pragma unroll
  for (int mi = 0; mi < 4; ++mi)
#pragma unroll
    for (int r = 0; r < 4; ++r) {
      size_t node = (size_t)node0 + mi * 16 + lk * 4 + r;
      cvv[mi][r] = cvp[node * 128 + d];
      hov[mi][r] = hvp[node * 128 + d];
    }

  // ---- Phase 2 + pointwise, m-split into two passes (acc2 = 32 live regs each)
#pragma unroll
  for (int P = 0; P < 2; ++P) {
    f32x4 acc2[2][4];
#pragma unroll
    for (int mi = 0; mi < 2; ++mi)
#pragma unroll
      for (int j = 0; j < 4; ++j) acc2[mi][j] = f32x4{0.f,0.f,0.f,0.f};

#pragma unroll
    for (int kk = 0; kk < 8; ++kk) {
      s16x8 a[2];
#pragma unroll
      for (int mi = 0; mi < 2; ++mi)
        a[mi] = *(const s16x8*)(lds + SWZ2((P * 2 + mi) * 16 + l15, kk * 64 + lk * 16));
      const char* wb = (const char*)W2 + kk * 32768 + lk * 16;
#pragma unroll
      for (int j = 0; j < 4; ++j) {
        s16x8 bf = *(const s16x8*)(wb + (size_t)(16 * w + 128 * j + l15) * 64);
#pragma unroll
        for (int mi = 0; mi < 2; ++mi)
          acc2[mi][j] = __builtin_amdgcn_mfma_f32_16x16x32_bf16(a[mi], bf, acc2[mi][j], 0, 0, 0);
      }
    }

    // pointwise rows P*32 .. P*32+31
#pragma unroll
    for (int mi = 0; mi < 2; ++mi) {
#pragma unroll
      for (int r = 0; r < 4; ++r) {
        int m = (P * 2 + mi) * 16 + lk * 4 + r;
        size_t node = (size_t)node0 + m;
        int act = (int)((actmask >> m) & 1ull);
        float gi = acc2[mi][0][r] + bs[0];
        float gf = acc2[mi][1][r] + bs[1];
        float gg = acc2[mi][2][r] + bs[2];
        float go = acc2[mi][3][r] + bs[3];
        float i_ = fsig(gi), f_ = fsig(gf), o_ = fsig(go);
        float g_ = ftanh(gg);
        float co = cvv[P * 2 + mi][r];
        float ho = hov[P * 2 + mi][r];
        float cn = f_ * co + i_ * g_;
        float hn = o_ * ftanh(cn);
        hvo[node * 128 + d] = act ? hn : ho;
        cvo[node * 128 + d] = act ? cn : co;
      }
    }
  }
}

extern "C" void kernel_launch(void* const* d_in, const int* in_sizes, int n_in,
                              void* d_out, int out_size, void* d_ws, size_t ws_size,
                              hipStream_t stream) {
  const float* Hv   = (const float*)d_in[0];
  const float* hvv  = (const float*)d_in[1];
  const float* xv   = (const float*)d_in[2];
  const float* hvp  = (const float*)d_in[3];
  const float* cvp  = (const float*)d_in[4];
  const int*   tsm  = (const int*)d_in[5];
  const float* Wpos = (const float*)d_in[6];
  const float* bpos = (const float*)d_in[7];
  const float* Whid = (const float*)d_in[8];
  const float* bhid = (const float*)d_in[9];
  const float* Wih  = (const float*)d_in[10];
  const float* bih  = (const float*)d_in[11];
  const float* Whh  = (const float*)d_in[12];
  const float* bhh  = (const float*)d_in[13];

  unsigned short* wsWh2 = (unsigned short*)d_ws;   // 32768 bf16
  unsigned short* wsW2  = wsWh2 + 32768;           // 131072 bf16
  float* wsBias = (float*)(wsW2 + 131072);         // 512 f32

  prep_kernel<<<512, 256, 0, stream>>>(Whid, Wih, Whh, bih, bhh,
                                       wsWh2, wsW2, wsBias);

  float* hvo = (float*)d_out;
  float* cvo = hvo + (size_t)N_NODES * 128;
  node_rnn_kernel<<<N_NODES / BM, NTHREADS, 0, stream>>>(
      Hv, hvv, xv, hvp, cvp, tsm, Wpos, bpos, bhid,
      wsWh2, wsW2, wsBias, hvo, cvo);
}

// Round 7
// 296.709 us; speedup vs baseline: 4.0046x; 1.5117x over previous
//
#include <hip/hip_runtime.h>

#define N_NODES 262144
#define BM 64
#define NTHREADS 512

typedef short s16x8 __attribute__((ext_vector_type(8)));
typedef float f32x4 __attribute__((ext_vector_type(4)));

// 2 f32 -> packed bf16x2 in one VOP3 (T12 primitive).
static __device__ __forceinline__ unsigned cvtpk(float lo, float hi) {
  unsigned r;
  asm("v_cvt_pk_bf16_f32 %0, %1, %2" : "=v"(r) : "v"(lo), "v"(hi));
  return r;
}

static __device__ __forceinline__ unsigned short f2bf(float f) {
  union { float f; unsigned u; } v; v.f = f;
  unsigned u = v.u;
  u += 0x7FFFu + ((u >> 16) & 1u);   // round-to-nearest-even
  return (unsigned short)(u >> 16);
}

static __device__ __forceinline__ unsigned long long pack4bf(f32x4 v) {
  unsigned u0 = cvtpk(v.x, v.y);
  unsigned u1 = cvtpk(v.z, v.w);
  return (unsigned long long)u0 | ((unsigned long long)u1 << 32);
}

static __device__ __forceinline__ float fsig(float x) {
  return __builtin_amdgcn_rcpf(1.0f + __expf(-x));
}
static __device__ __forceinline__ float ftanh(float x) {
  return 2.0f * __builtin_amdgcn_rcpf(1.0f + __expf(-2.0f * x)) - 1.0f;
}

// Weight prep:
//  Wh2[kb][n][ki] (16 x 64 x 32 bf16)  = W_hid[n][kb*32+ki]
//  W2 [kb][n][ki] ( 8 x 512 x 32 bf16) = k<128 ? W_ih[n][k] : W_hh[n][k-128]
//  biasg[512] = b_ih + b_hh
__global__ void prep_kernel(const float* __restrict__ Whid, const float* __restrict__ Wih,
                            const float* __restrict__ Whh, const float* __restrict__ bih,
                            const float* __restrict__ bhh,
                            unsigned short* __restrict__ oWh2, unsigned short* __restrict__ oW2,
                            float* __restrict__ oBias) {
  int t = blockIdx.x * 256 + threadIdx.x;
  if (t < 32768) {
    int kb = t >> 11, n = (t >> 5) & 63, ki = t & 31;
    oWh2[t] = f2bf(Whid[n * 512 + kb * 32 + ki]);
  }
  if (t < 131072) {
    int kb = t >> 14, n = (t >> 5) & 511, ki = t & 31;
    int k = kb * 32 + ki;
    float v = (k < 128) ? Wih[n * 128 + k] : Whh[n * 128 + (k - 128)];
    oW2[t] = f2bf(v);
  }
  if (t < 512) oBias[t] = bih[t] + bhh[t];
}

// Astage: 64 rows x 512 bf16 (1024B rows). XOR-swizzle spreads 16-row-strided
// b128 column reads over 8 16B slots (G4).
#define SWZA(m, b) ((((m) * 1024) + (b)) ^ (((m) & 7) << 4))
// A2: 64 rows x 256 bf16 (512B rows) = [e_v(64) | a_v(64) | hv(128)]. Aliases lds[0:32KB].
#define SWZ2(m, b) ((((m) * 512) + (b)) ^ (((m) & 7) << 4))

__global__ __launch_bounds__(NTHREADS, 4) void node_rnn_kernel(
    const float* __restrict__ Hv, const float* __restrict__ hvv,
    const float* __restrict__ xv, const float* __restrict__ hvp,
    const float* __restrict__ cvp, const int* __restrict__ tsm,
    const float* __restrict__ Wpos, const float* __restrict__ bpos,
    const float* __restrict__ bhid,
    const unsigned short* __restrict__ Wh2,
    const unsigned short* __restrict__ W2,
    const float* __restrict__ biasg,
    float* __restrict__ hvo, float* __restrict__ cvo)
{
  __shared__ __align__(16) char lds[65536];

  const int tid = threadIdx.x;
  const int w   = tid >> 6;      // wave 0..7
  const int l   = tid & 63;
  const int l15 = l & 15;
  const int lk  = l >> 4;        // k-group 0..3
  const int wr  = w >> 2;        // phase-1 m-half
  const int wc  = w & 3;         // phase-1 n-slice (16 cols)
  const int node0 = blockIdx.x * BM;
  const int d   = 16 * w + l15;  // phase-2/3 gate-dim slice

  // ---- Stage [hvv|Hv] (64 x 512 f32) -> bf16 Astage; coalesced f32x4, cvt_pk once
#pragma unroll
  for (int it = 0; it < 16; ++it) {
    int p = tid + it * NTHREADS;            // 64 rows x 128 f32x4-chunks
    int m = p >> 7, ch = p & 127;
    const float* src = (ch < 64) ? (hvv + (size_t)(node0 + m) * 256 + ch * 4)
                                 : (Hv  + (size_t)(node0 + m) * 256 + (ch - 64) * 4);
    f32x4 v = *(const f32x4*)src;
    *(unsigned long long*)(lds + SWZA(m, ch * 8)) = pack4bf(v);
  }

  // ---- small per-tile loads behind the stage loads (covered by phase 1)
  unsigned long long actmask = __ballot(tsm[node0 + l] == 1);  // bit m = row m active

  unsigned evp[4];     // e_v as packed bf16 pairs
#pragma unroll
  for (int it = 0; it < 4; ++it) {
    int p = tid + it * NTHREADS;            // 64 rows x 32 pairs
    int m = p >> 5, jp = p & 31;
    float x0 = xv[(size_t)(node0 + m) * 2 + 0];
    float x1 = xv[(size_t)(node0 + m) * 2 + 1];
    float e0 = fmaxf(x0 * Wpos[(2*jp  )*2] + x1 * Wpos[(2*jp  )*2+1] + bpos[2*jp  ], 0.f);
    float e1 = fmaxf(x0 * Wpos[(2*jp+1)*2] + x1 * Wpos[(2*jp+1)*2+1] + bpos[2*jp+1], 0.f);
    evp[it] = cvtpk(e0, e1);
  }
  f32x4 hvc[4];        // hv_tm1 for the A2 tile
#pragma unroll
  for (int it = 0; it < 4; ++it) {
    int p = tid + it * NTHREADS;            // 64 rows x 32 f32x4-chunks
    int m = p >> 5, c4 = p & 31;
    hvc[it] = *(const f32x4*)(hvp + (size_t)(node0 + m) * 128 + c4 * 4);
  }

  __syncthreads();   // B1: Astage complete

  // ---- Phase 1: a_v = relu([hvv|Hv] @ Wh^T + bhid); wave (wr,wc): rows wr*32+[0,32), cols wc*16+[0,16)
  f32x4 acc[2] = {f32x4{0.f,0.f,0.f,0.f}, f32x4{0.f,0.f,0.f,0.f}};
  {
    const char* whb = (const char*)Wh2 + (wc * 16 + l15) * 64 + lk * 16;
#pragma unroll
    for (int ks = 0; ks < 16; ++ks) {
      s16x8 bf = *(const s16x8*)(whb + ks * 4096);
#pragma unroll
      for (int mi = 0; mi < 2; ++mi) {
        int m = wr * 32 + mi * 16 + l15;
        s16x8 af = *(const s16x8*)(lds + SWZA(m, ks * 64 + lk * 16));
        acc[mi] = __builtin_amdgcn_mfma_f32_16x16x32_bf16(af, bf, acc[mi], 0, 0, 0);
      }
    }
  }

  __syncthreads();   // B2: all Astage reads done; safe to overwrite with A2

  // ---- Build A2 = [e_v | a_v | hv] bf16
#pragma unroll
  for (int it = 0; it < 4; ++it) {
    int p = tid + it * NTHREADS;
    int m = p >> 5, jp = p & 31;
    *(unsigned*)(lds + SWZ2(m, jp * 4)) = evp[it];
  }
#pragma unroll
  for (int it = 0; it < 4; ++it) {
    int p = tid + it * NTHREADS;
    int m = p >> 5, c4 = p & 31;
    *(unsigned long long*)(lds + SWZ2(m, 256 + c4 * 8)) = pack4bf(hvc[it]);
  }
  {
    float bb = bhid[wc * 16 + l15];
    int cb = (64 + wc * 16 + l15) * 2;
#pragma unroll
    for (int mi = 0; mi < 2; ++mi) {
#pragma unroll
      for (int r = 0; r < 4; ++r) {
        int m = wr * 32 + mi * 16 + lk * 4 + r;
        float av = fmaxf(acc[mi][r] + bb, 0.0f);
        *(unsigned short*)(lds + SWZ2(m, cb)) = f2bf(av);
      }
    }
  }
  __syncthreads();   // B3: A2 complete

  float bs[4];
#pragma unroll
  for (int j = 0; j < 4; ++j) bs[j] = biasg[128 * j + d];

  // ---- Phase 2: gates = A2(64x256) @ [Wih;Whh]^T; wave w owns d-slice [16w,16w+16) of all 4 gates
  f32x4 acc2[4][4];
#pragma unroll
  for (int mi = 0; mi < 4; ++mi)
#pragma unroll
    for (int j = 0; j < 4; ++j) acc2[mi][j] = f32x4{0.f,0.f,0.f,0.f};

#pragma unroll
  for (int kk = 0; kk < 8; ++kk) {
    s16x8 a[4];
#pragma unroll
    for (int mi = 0; mi < 4; ++mi)
      a[mi] = *(const s16x8*)(lds + SWZ2(mi * 16 + l15, kk * 64 + lk * 16));
    const char* wb = (const char*)W2 + kk * 32768 + lk * 16;
#pragma unroll
    for (int j = 0; j < 4; ++j) {
      s16x8 bf = *(const s16x8*)(wb + (size_t)(16 * w + 128 * j + l15) * 64);
#pragma unroll
      for (int mi = 0; mi < 4; ++mi)
        acc2[mi][j] = __builtin_amdgcn_mfma_f32_16x16x32_bf16(a[mi], bf, acc2[mi][j], 0, 0, 0);
    }
  }

  // ---- Phase 3: LSTM pointwise + mask select. acc2[mi][j]: gate j (i,f,g,o)
#pragma unroll
  for (int mi = 0; mi < 4; ++mi) {
#pragma unroll
    for (int r = 0; r < 4; ++r) {
      int m = mi * 16 + lk * 4 + r;
      size_t node = (size_t)node0 + m;
      int act = (int)((actmask >> m) & 1ull);
      float gi = acc2[mi][0][r] + bs[0];
      float gf = acc2[mi][1][r] + bs[1];
      float gg = acc2[mi][2][r] + bs[2];
      float go = acc2[mi][3][r] + bs[3];
      float i_ = fsig(gi), f_ = fsig(gf), o_ = fsig(go);
      float g_ = ftanh(gg);
      float co = cvp[node * 128 + d];
      float ho = hvp[node * 128 + d];
      float cn = f_ * co + i_ * g_;
      float hn = o_ * ftanh(cn);
      hvo[node * 128 + d] = act ? hn : ho;
      cvo[node * 128 + d] = act ? cn : co;
    }
  }
}

extern "C" void kernel_launch(void* const* d_in, const int* in_sizes, int n_in,
                              void* d_out, int out_size, void* d_ws, size_t ws_size,
                              hipStream_t stream) {
  const float* Hv   = (const float*)d_in[0];
  const float* hvv  = (const float*)d_in[1];
  const float* xv   = (const float*)d_in[2];
  const float* hvp  = (const float*)d_in[3];
  const float* cvp  = (const float*)d_in[4];
  const int*   tsm  = (const int*)d_in[5];
  const float* Wpos = (const float*)d_in[6];
  const float* bpos = (const float*)d_in[7];
  const float* Whid = (const float*)d_in[8];
  const float* bhid = (const float*)d_in[9];
  const float* Wih  = (const float*)d_in[10];
  const float* bih  = (const float*)d_in[11];
  const float* Whh  = (const float*)d_in[12];
  const float* bhh  = (const float*)d_in[13];

  unsigned short* wsWh2 = (unsigned short*)d_ws;   // 32768 bf16
  unsigned short* wsW2  = wsWh2 + 32768;           // 131072 bf16
  float* wsBias = (float*)(wsW2 + 131072);         // 512 f32

  prep_kernel<<<512, 256, 0, stream>>>(Whid, Wih, Whh, bih, bhh,
                                       wsWh2, wsW2, wsBias);

  float* hvo = (float*)d_out;
  float* cvo = hvo + (size_t)N_NODES * 128;
  node_rnn_kernel<<<N_NODES / BM, NTHREADS, 0, stream>>>(
      Hv, hvv, xv, hvp, cvp, tsm, Wpos, bpos, bhid,
      wsWh2, wsW2, wsBias, hvo, cvo);
}